// Round 5
// baseline (368.510 us; speedup 1.0000x reference)
//
#include <hip/hip_runtime.h>

// ModelQuantLinear: int8-act × int4-weight per-tensor quantized linear, 8192×4096 @ 4096×4096^T.
// Exact integer GEMM via mfma_i32_16x16x64_i8, 256x256 tile, BK=128B, whole-tile double buffer,
// ONE barrier per K-tile; intra-tile reads/MFMA free-run (compiler-counted lgkmcnt) so the LDS
// pipe overlaps the matrix pipe across the 8 waves.

typedef int v4i __attribute__((ext_vector_type(4)));

#define AS1(p) ((const __attribute__((address_space(1))) void*)(p))
#define AS3(p) ((__attribute__((address_space(3))) void*)(p))

#define GM 8192
#define GN 4096
#define GK 4096
#define NBN 16   // 4096/256 col tiles
#define NWG 512  // (8192/256)*(4096/256)

// ---------------- max|x| (float4 grid-stride, wave+block reduce, 1 atomic/block) ------------
__global__ __launch_bounds__(256) void maxabs_kernel(const float* __restrict__ x, int n4,
                                                     unsigned* __restrict__ slot) {
  __shared__ float red[4];
  int tid = blockIdx.x * blockDim.x + threadIdx.x;
  int stride = gridDim.x * blockDim.x;
  float m = 0.0f;
  const float4* x4 = (const float4*)x;
  for (int i = tid; i < n4; i += stride) {
    float4 v = x4[i];
    m = fmaxf(m, fmaxf(fmaxf(fabsf(v.x), fabsf(v.y)), fmaxf(fabsf(v.z), fabsf(v.w))));
  }
  for (int off = 32; off; off >>= 1) m = fmaxf(m, __shfl_xor(m, off));
  if ((threadIdx.x & 63) == 0) red[threadIdx.x >> 6] = m;
  __syncthreads();
  if (threadIdx.x == 0) {
    float b = fmaxf(fmaxf(red[0], red[1]), fmaxf(red[2], red[3]));
    atomicMax(slot, __float_as_uint(b));
  }
}

// ---------------- per-tensor quantize to int8 storage (reciprocal-mul) ----------------------
__global__ __launch_bounds__(256) void quant_kernel(const float* __restrict__ x,
                                                    signed char* __restrict__ q, int n4,
                                                    const unsigned* __restrict__ slot,
                                                    float qmaxv, float qlo, float qhi) {
  float s = fmaxf(__uint_as_float(*slot) / qmaxv, 1e-8f);
  float inv = 1.0f / s;
  int tid = blockIdx.x * blockDim.x + threadIdx.x;
  int stride = gridDim.x * blockDim.x;
  const float4* x4 = (const float4*)x;
  int* q4 = (int*)q;
  for (int i = tid; i < n4; i += stride) {
    float4 v = x4[i];
    int a0 = (int)fminf(fmaxf(rintf(v.x * inv), qlo), qhi);
    int a1 = (int)fminf(fmaxf(rintf(v.y * inv), qlo), qhi);
    int a2 = (int)fminf(fmaxf(rintf(v.z * inv), qlo), qhi);
    int a3 = (int)fminf(fmaxf(rintf(v.w * inv), qlo), qhi);
    q4[i] = (a0 & 255) | ((a1 & 255) << 8) | ((a2 & 255) << 16) | ((a3 & 255) << 24);
  }
}

// ---------------- i8 GEMM, 256x256 tile, BK=128 B, 8 waves (2Mx4N) ---------------------------
// Per tile t (read buffer db=t&1; stages during region t fill ndb for t+1):
//   gate: lgkmcnt(0) [t's-1 reads drained]; vmcnt(0) [tile t's 8 staging loads landed];
//         s_barrier  -> all waves' stage data visible, all prior reads done.
//   region: issue 8 stages for t+1 (write ndb; its readers drained at this gate);
//           then 24 ds_read_b128 + 64 MFMA free-run, one-phase-ahead reads, NO barriers/waits
//           (compiler inserts counted lgkmcnt from data deps).
// Hazard audit: intra-tile reads(db) vs stage-writes(ndb) disjoint; stage issued in region t
// overwrites the buffer last read in region t-1, drained at this tile's gate. vmcnt(0) at the
// gate is ~free: the 8 loads had the entire previous compute region (~2800 cyc >> HBM 900) in
// flight. Swizzle: 16B granule g_phys = g_log ^ (row&7), inverse-applied on global source.
__global__ __launch_bounds__(512, 2) void gemm_i8_kernel(const signed char* __restrict__ Xq,
                                                         const signed char* __restrict__ Wq,
                                                         const float* __restrict__ bias,
                                                         const unsigned* __restrict__ slots,
                                                         float* __restrict__ Y,
                                                         unsigned* __restrict__ maxY) {
  __shared__ signed char smem[131072];
  const int tid = threadIdx.x;
  const int wid = tid >> 6, lane = tid & 63;
  const int wr = wid >> 2, wc = wid & 3;
  const int lr = lane & 15, lg = lane >> 4;

  // XCD-aware bijective swizzle (512 % 8 == 0)
  const int bid = (int)blockIdx.x;
  const int swz = (bid & 7) * (NWG / 8) + (bid >> 3);
  const int brow = (swz / NBN) * 256;
  const int bcol = (swz % NBN) * 256;

  // staging thread map: row-in-half, inverse-swizzled source granule
  const int srr = tid >> 3;
  const int sgl = (tid & 7) ^ (srr & 7);

  // per-frag LDS row offsets / swizzle keys (invariant over tiles & kslices)
  int aoff[4], asw[4], boff[4], bsw[4];
#pragma unroll
  for (int mm = 0; mm < 4; ++mm) {
    int hr = wr * 64 + mm * 16 + lr;
    aoff[mm] = hr * 128;
    asw[mm] = hr & 7;
  }
#pragma unroll
  for (int nn = 0; nn < 4; ++nn) {
    int hr = wc * 32 + (nn & 1) * 16 + lr;
    boff[nn] = hr * 128;
    bsw[nn] = hr & 7;
  }

#define ASLOT(db, h) (smem + ((db) * 2 + (h)) * 16384)
#define BSLOT(db, h) (smem + 65536 + ((db) * 2 + (h)) * 16384)
// one half-tile (128 rows x 128 B) = 2 x global_load_lds(16B) per wave
#define STAGE(gptr, grow0, kofs, slot)                                                        \
  {                                                                                           \
    const signed char* _s0 = (gptr) + (size_t)((grow0) + srr) * GK + (kofs) + sgl * 16;       \
    __builtin_amdgcn_global_load_lds(AS1(_s0), AS3((slot) + wid * 1024), 16, 0, 0);           \
    __builtin_amdgcn_global_load_lds(AS1(_s0 + (size_t)64 * GK),                              \
                                     AS3((slot) + 8192 + wid * 1024), 16, 0, 0);              \
  }
#define LDA(mm, db, h, kk) \
  *(const v4i*)(ASLOT(db, h) + aoff[mm] + ((((kk)*4 + lg) ^ asw[mm]) << 4))
#define LDB(nn, db, kk) \
  *(const v4i*)(BSLOT(db, (nn) >> 1) + boff[nn] + ((((kk)*4 + lg) ^ bsw[nn]) << 4))
#define MFMA16(arow, AF, BF)                                                                  \
  __builtin_amdgcn_s_setprio(1);                                                              \
  _Pragma("unroll") for (int mm = 0; mm < 4; ++mm)                                            \
      _Pragma("unroll") for (int nn = 0; nn < 4; ++nn)                                        \
          acc[(arow) + mm][nn] =                                                              \
      __builtin_amdgcn_mfma_i32_16x16x64_i8(AF[mm], BF[nn], acc[(arow) + mm][nn], 0, 0, 0);   \
  __builtin_amdgcn_s_setprio(0);

  // prologue: tile 0's four halves
  STAGE(Wq, bcol, 0, BSLOT(0, 0));
  STAGE(Wq, bcol + 128, 0, BSLOT(0, 1));
  STAGE(Xq, brow, 0, ASLOT(0, 0));
  STAGE(Xq, brow + 128, 0, ASLOT(0, 1));

  v4i acc[8][4] = {};

#pragma unroll 2
  for (int t = 0; t < 32; ++t) {
    const int db = t & 1, ndb = db ^ 1;
    const int kof = (t + 1) * 128;

    // ---- gate (the only barrier per tile)
    asm volatile("s_waitcnt lgkmcnt(0)" ::: "memory");
    asm volatile("s_waitcnt vmcnt(0)" ::: "memory");
    __builtin_amdgcn_s_barrier();
    asm volatile("" ::: "memory");

    // ---- issue next tile's stages (write ndb; readers of ndb drained at this gate)
    if (t < 31) {
      STAGE(Wq, bcol, kof, BSLOT(ndb, 0));
      STAGE(Wq, bcol + 128, kof, BSLOT(ndb, 1));
      STAGE(Xq, brow, kof, ASLOT(ndb, 0));
      STAGE(Xq, brow + 128, kof, ASLOT(ndb, 1));
    }

    // ---- free-run compute: one-phase-ahead reads, compiler-counted lgkmcnt, no barriers
    v4i af0[4], af1[4], bf0[4], bf1[4];
#pragma unroll
    for (int mm = 0; mm < 4; ++mm) af0[mm] = LDA(mm, db, 0, 0);
#pragma unroll
    for (int nn = 0; nn < 4; ++nn) bf0[nn] = LDB(nn, db, 0);
#pragma unroll
    for (int mm = 0; mm < 4; ++mm) af1[mm] = LDA(mm, db, 1, 0);
    MFMA16(0, af0, bf0)
#pragma unroll
    for (int mm = 0; mm < 4; ++mm) af0[mm] = LDA(mm, db, 0, 1);
#pragma unroll
    for (int nn = 0; nn < 4; ++nn) bf1[nn] = LDB(nn, db, 1);
    MFMA16(4, af1, bf0)
#pragma unroll
    for (int mm = 0; mm < 4; ++mm) af1[mm] = LDA(mm, db, 1, 1);
    MFMA16(0, af0, bf1)
    MFMA16(4, af1, bf1)
  }

  // Epilogue: y = acc*(s_in*s_w) + round(b/s_b)*s_b ; track max|y| (block-reduced atomic)
  float s_in = fmaxf(__uint_as_float(slots[0]) / 127.0f, 1e-8f);
  float s_w = fmaxf(__uint_as_float(slots[1]) / 7.0f, 1e-8f);
  float s_b = s_in * s_w;
  float lmax = 0.0f;
#pragma unroll
  for (int n = 0; n < 4; ++n) {
    int o = bcol + (n >> 1) * 128 + wc * 32 + (n & 1) * 16 + lr;
    float bdq = rintf(bias[o] / s_b) * s_b;
#pragma unroll
    for (int m = 0; m < 8; ++m) {
      int t0 = brow + (m >> 2) * 128 + wr * 64 + (m & 3) * 16 + (lg << 2);
#pragma unroll
      for (int r2 = 0; r2 < 4; ++r2) {
        float yv = (float)acc[m][n][r2] * s_b + bdq;
        Y[(size_t)(t0 + r2) * GN + o] = yv;
        lmax = fmaxf(lmax, fabsf(yv));
      }
    }
  }
  for (int off = 32; off; off >>= 1) lmax = fmaxf(lmax, __shfl_xor(lmax, off));
  // fred sits in smem[0..32) = ASLOT(0,0); tile 31 read db=1 buffers only -> no collision.
  float* fred = (float*)smem;
  if (lane == 0) fred[wid] = lmax;
  __syncthreads();
  if (tid == 0) {
    float m = fred[0];
#pragma unroll
    for (int i = 1; i < 8; ++i) m = fmaxf(m, fred[i]);
    atomicMax(maxY, __float_as_uint(m));
  }
#undef STAGE
#undef ASLOT
#undef BSLOT
#undef LDA
#undef LDB
#undef MFMA16
}

// ---------------- output quant in-place on d_out --------------------------------------------
__global__ __launch_bounds__(256) void quant_out_kernel(float* __restrict__ y, int n4,
                                                        const unsigned* __restrict__ slot) {
  float s = fmaxf(__uint_as_float(*slot) / 127.0f, 1e-8f);
  float inv = 1.0f / s;
  int tid = blockIdx.x * blockDim.x + threadIdx.x;
  int stride = gridDim.x * blockDim.x;
  float4* y4 = (float4*)y;
  for (int i = tid; i < n4; i += stride) {
    float4 v = y4[i];
    v.x = fminf(fmaxf(rintf(v.x * inv), -128.0f), 127.0f) * s;
    v.y = fminf(fmaxf(rintf(v.y * inv), -128.0f), 127.0f) * s;
    v.z = fminf(fmaxf(rintf(v.z * inv), -128.0f), 127.0f) * s;
    v.w = fminf(fmaxf(rintf(v.w * inv), -128.0f), 127.0f) * s;
    y4[i] = v;
  }
}

extern "C" void kernel_launch(void* const* d_in, const int* in_sizes, int n_in,
                              void* d_out, int out_size, void* d_ws, size_t ws_size,
                              hipStream_t stream) {
  const float* inp = (const float*)d_in[0];  // [8192,4096]
  const float* W = (const float*)d_in[1];    // [4096,4096]
  const float* b = (const float*)d_in[2];    // [4096]
  float* out = (float*)d_out;                // [8192,4096]

  unsigned* slots = (unsigned*)d_ws;  // [0]=max|X|, [1]=max|W|, [2]=max|Y| (float bits)
  signed char* Xq = (signed char*)d_ws + 256;
  signed char* Wq = Xq + (size_t)GM * GK;

  const int nX = GM * GK;
  const int nW = GN * GK;

  // zero the atomic-max slots (ws is NOT re-poisoned between timed replays)
  hipMemsetAsync(d_ws, 0, 16, stream);

  maxabs_kernel<<<1024, 256, 0, stream>>>(inp, nX / 4, slots + 0);
  maxabs_kernel<<<512, 256, 0, stream>>>(W, nW / 4, slots + 1);

  quant_kernel<<<1024, 256, 0, stream>>>(inp, Xq, nX / 4, slots + 0, 127.0f, -128.0f, 127.0f);
  quant_kernel<<<512, 256, 0, stream>>>(W, Wq, nW / 4, slots + 1, 7.0f, -8.0f, 7.0f);

  gemm_i8_kernel<<<NWG, 512, 0, stream>>>(Xq, Wq, b, slots, out, slots + 2);

  quant_out_kernel<<<1024, 256, 0, stream>>>(out, (GM * GN) / 4, slots + 2);
}